// Round 1
// baseline (16910.826 us; speedup 1.0000x reference)
//
#include <hip/hip_runtime.h>

#define NCU 256
#define WGS 512
#define Bb  128
#define Tt  512
#define Ff  512
#define Hh  1024
#define BH  (Bb*Hh)

typedef __attribute__((ext_vector_type(8))) short short8;
typedef __attribute__((ext_vector_type(4))) float f32x4;

__device__ __forceinline__ short f2bf(float f){
  union { float fv; unsigned u; } v; v.fv = f;
  unsigned r = v.u + 0x7fffu + ((v.u >> 16) & 1u);   // RNE
  return (short)(r >> 16);
}

__device__ __forceinline__ f32x4 mfma16(short8 a, short8 b, f32x4 c){
  return __builtin_amdgcn_mfma_f32_16x16x32_bf16(a, b, c, 0, 0, 0);
}

__device__ __forceinline__ void gridbar(unsigned* cnt, unsigned target){
  __syncthreads();
  if (threadIdx.x == 0){
    __hip_atomic_fetch_add(cnt, 1u, __ATOMIC_RELEASE, __HIP_MEMORY_SCOPE_AGENT);
    while (__hip_atomic_load(cnt, __ATOMIC_RELAXED, __HIP_MEMORY_SCOPE_AGENT) < target)
      __builtin_amdgcn_s_sleep(1);
    (void)__hip_atomic_load(cnt, __ATOMIC_ACQUIRE, __HIP_MEMORY_SCOPE_AGENT);
  }
  __syncthreads();
}

// LDS layout (dynamic, 128 KiB total):
//   Lhh1: [32 ch][64 lane][8]  bf16  32768 B @ 0
//   Lih2: 32768 B @ 32768
//   Lhh2: 32768 B @ 65536
//   Lih1: [16 ch][64][8]       16384 B @ 98304
//   F1  : [128][16] f32         8192 B @ 114688
//   F2  : [128][16] f32         8192 B @ 122880   -> 131072 total
__global__ void __launch_bounds__(WGS) lstm_persistent(
    const float* __restrict__ x,
    const float* __restrict__ Wih1, const float* __restrict__ Whh1,
    const float* __restrict__ bih1, const float* __restrict__ bhh1,
    const float* __restrict__ Wih2, const float* __restrict__ Whh2,
    const float* __restrict__ bih2, const float* __restrict__ bhh2,
    short* __restrict__ h1buf, short* __restrict__ h2buf,
    float* __restrict__ h2f32, unsigned* __restrict__ barcnt)
{
  extern __shared__ char lds[];
  short* Lhh1 = (short*)(lds);
  short* Lih2 = (short*)(lds + 32768);
  short* Lhh2 = (short*)(lds + 65536);
  short* Lih1 = (short*)(lds + 98304);
  float* F1   = (float*)(lds + 114688);
  float* F2   = (float*)(lds + 122880);

  const int cu   = blockIdx.x;      // 0..255, owns h-cols [4cu, 4cu+4)
  const int tid  = threadIdx.x;
  const int lane = tid & 63;
  const int wv   = tid >> 6;        // wave = batch row-tile 0..7

  // ---- stage weights fp32->bf16 into LDS, MFMA B-fragment order ----
  // frag (ch, lane): col = lane&15 -> gate gt=col>>2, jj=col&3 ; k = ch*32+(lane>>4)*8+e
  for (int i = tid; i < 7168; i += WGS) {
    int mm, fi;
    if      (i < 2048) { mm=0; fi=i; }
    else if (i < 4096) { mm=1; fi=i-2048; }
    else if (i < 6144) { mm=2; fi=i-4096; }
    else               { mm=3; fi=i-6144; }
    const int ch = fi >> 6, ln = fi & 63;
    const int cl = ln & 15, kg = ln >> 4;
    const int grow = (cl >> 2) * Hh + cu*4 + (cl & 3);
    const float* src; short* dst; int K;
    if      (mm==0){ src=Whh1; dst=Lhh1; K=Hh; }
    else if (mm==1){ src=Wih2; dst=Lih2; K=Hh; }
    else if (mm==2){ src=Whh2; dst=Lhh2; K=Hh; }
    else           { src=Wih1; dst=Lih1; K=Ff; }
    const float* s = src + (size_t)grow*K + ch*32 + kg*8;
    short8 v;
    #pragma unroll
    for (int e=0; e<8; ++e) v[e] = f2bf(s[e]);
    *(short8*)(dst + (size_t)fi*8) = v;
  }
  __syncthreads();

  // per-thread LSTM-update ownership: (batch ub, local col uj)
  const int ub = tid >> 2;
  const int uj = tid & 3;
  const int gcol = cu*4 + uj;
  const float b1s0 = bih1[0*Hh+gcol] + bhh1[0*Hh+gcol];
  const float b1s1 = bih1[1*Hh+gcol] + bhh1[1*Hh+gcol];
  const float b1s2 = bih1[2*Hh+gcol] + bhh1[2*Hh+gcol];
  const float b1s3 = bih1[3*Hh+gcol] + bhh1[3*Hh+gcol];
  const float b2s0 = bih2[0*Hh+gcol] + bhh2[0*Hh+gcol];
  const float b2s1 = bih2[1*Hh+gcol] + bhh2[1*Hh+gcol];
  const float b2s2 = bih2[2*Hh+gcol] + bhh2[2*Hh+gcol];
  const float b2s3 = bih2[3*Hh+gcol] + bhh2[3*Hh+gcol];
  float c1 = 0.f, c2 = 0.f;

  // A-fragment addressing: row = wv*16 + (lane&15), k-run base = (lane>>4)*8
  const int r0  = wv*16 + (lane & 15);
  const int kg8 = (lane >> 4) * 8;

  // Phase p: layer1 step p (p<Tt) + layer2 step p-1 (p>0). One grid barrier per phase.
  for (int p = 0; p <= Tt; ++p) {
    const short* h1p = h1buf + ((p+1)&1)*BH;   // h1[p-1]
    const short* h2p = h2buf + (p&1)*BH;       // h2[p-2]

    f32x4 a1x={0.f,0.f,0.f,0.f}, a1h={0.f,0.f,0.f,0.f};
    f32x4 a2a={0.f,0.f,0.f,0.f}, a2b={0.f,0.f,0.f,0.f};

    if (p < Tt) {                               // x_t @ W_ih1^T  (K=512)
      const float* xb = x + ((size_t)r0*Tt + p)*Ff + kg8;
      #pragma unroll 4
      for (int ch=0; ch<16; ++ch) {
        float4 u0 = *(const float4*)(xb + ch*32);
        float4 u1 = *(const float4*)(xb + ch*32 + 4);
        short8 a;
        a[0]=f2bf(u0.x); a[1]=f2bf(u0.y); a[2]=f2bf(u0.z); a[3]=f2bf(u0.w);
        a[4]=f2bf(u1.x); a[5]=f2bf(u1.y); a[6]=f2bf(u1.z); a[7]=f2bf(u1.w);
        a1x = mfma16(a, *(const short8*)(Lih1 + (ch*64+lane)*8), a1x);
      }
    }
    {                                           // h1[p-1] feeds W_hh1 (G1) and W_ih2 (G2)
      const short* hr = h1p + r0*Hh + kg8;
      #pragma unroll 8
      for (int ch=0; ch<32; ++ch) {
        short8 a = *(const short8*)(hr + ch*32);
        a1h = mfma16(a, *(const short8*)(Lhh1 + (ch*64+lane)*8), a1h);
        a2a = mfma16(a, *(const short8*)(Lih2 + (ch*64+lane)*8), a2a);
      }
    }
    {                                           // h2[p-2] @ W_hh2^T
      const short* hr = h2p + r0*Hh + kg8;
      #pragma unroll 8
      for (int ch=0; ch<32; ++ch) {
        short8 a = *(const short8*)(hr + ch*32);
        a2b = mfma16(a, *(const short8*)(Lhh2 + (ch*64+lane)*8), a2b);
      }
    }

    // dump gate tiles to LDS (C/D layout: col=lane&15, row=(lane>>4)*4+r)
    const int drow = wv*16 + ((lane>>4)<<2);
    const int dcol = lane & 15;
    #pragma unroll
    for (int r=0;r<4;++r){
      F1[(drow+r)*16 + dcol] = a1x[r] + a1h[r];
      F2[(drow+r)*16 + dcol] = a2a[r] + a2b[r];
    }
    __syncthreads();

    if (p < Tt) {                               // layer-1 update, step p
      float gi = F1[ub*16 + uj     ] + b1s0;
      float gf = F1[ub*16 + uj + 4 ] + b1s1;
      float gg = F1[ub*16 + uj + 8 ] + b1s2;
      float go = F1[ub*16 + uj + 12] + b1s3;
      float iv = 1.f/(1.f+__expf(-gi));
      float fv = 1.f/(1.f+__expf(-gf));
      float gv = tanhf(gg);
      float ov = 1.f/(1.f+__expf(-go));
      c1 = fv*c1 + iv*gv;
      h1buf[(p&1)*BH + ub*Hh + gcol] = f2bf(ov*tanhf(c1));
    }
    if (p > 0) {                                // layer-2 update, step p-1
      float gi = F2[ub*16 + uj     ] + b2s0;
      float gf = F2[ub*16 + uj + 4 ] + b2s1;
      float gg = F2[ub*16 + uj + 8 ] + b2s2;
      float go = F2[ub*16 + uj + 12] + b2s3;
      float iv = 1.f/(1.f+__expf(-gi));
      float fv = 1.f/(1.f+__expf(-gf));
      float gv = tanhf(gg);
      float ov = 1.f/(1.f+__expf(-go));
      c2 = fv*c2 + iv*gv;
      float hv = ov*tanhf(c2);
      h2buf[((p+1)&1)*BH + ub*Hh + gcol] = f2bf(hv);
      if (p == Tt) h2f32[ub*Hh + gcol] = hv;    // exact fp32 copy of final h2
    }
    gridbar(barcnt, (unsigned)(NCU*(p+1)));
  }
}

__global__ void final_linear(const float* __restrict__ h2, const float* __restrict__ Wl,
                             const float* __restrict__ bl, float* __restrict__ out){
  __shared__ float red[256];
  const int b = blockIdx.x, t = threadIdx.x;
  float s = 0.f;
  for (int k = t; k < Hh; k += 256) s += h2[(size_t)b*Hh + k] * Wl[k];
  red[t] = s; __syncthreads();
  for (int off=128; off>0; off>>=1){ if (t<off) red[t]+=red[t+off]; __syncthreads(); }
  if (t==0) out[b] = red[0] + bl[0];
}

extern "C" void kernel_launch(void* const* d_in, const int* in_sizes, int n_in,
                              void* d_out, int out_size, void* d_ws, size_t ws_size,
                              hipStream_t stream) {
  (void)in_sizes; (void)n_in; (void)out_size;
  const float* x    = (const float*)d_in[0];
  const float* Wih1 = (const float*)d_in[1];
  const float* Whh1 = (const float*)d_in[2];
  const float* bih1 = (const float*)d_in[3];
  const float* bhh1 = (const float*)d_in[4];
  const float* Wih2 = (const float*)d_in[5];
  const float* Whh2 = (const float*)d_in[6];
  const float* bih2 = (const float*)d_in[7];
  const float* bhh2 = (const float*)d_in[8];
  const float* Wlin = (const float*)d_in[9];
  const float* blin = (const float*)d_in[10];
  float* out = (float*)d_out;

  char* ws = (char*)d_ws;
  short*    h1buf  = (short*)(ws);                    // [2][128][1024] bf16
  short*    h2buf  = (short*)(ws + 524288);           // [2][128][1024] bf16
  float*    h2f32  = (float*)(ws + 1048576);          // [128][1024] f32
  unsigned* barcnt = (unsigned*)(ws + 1572864);
  const size_t WS_USED = 1572864 + 256;
  if (ws_size < WS_USED) return;                      // fail loudly via unwritten output

  hipMemsetAsync(d_ws, 0, WS_USED, stream);           // zero h state + barrier each call
  hipFuncSetAttribute(reinterpret_cast<const void*>(lstm_persistent),
                      hipFuncAttributeMaxDynamicSharedMemorySize, 131072);
  lstm_persistent<<<dim3(NCU), dim3(WGS), 131072, stream>>>(
      x, Wih1, Whh1, bih1, bhh1, Wih2, Whh2, bih2, bhh2,
      h1buf, h2buf, h2f32, barcnt);
  final_linear<<<dim3(Bb), dim3(256), 0, stream>>>(h2f32, Wlin, blin, out);
}

// Round 2
// 16153.995 us; speedup vs baseline: 1.0469x; 1.0469x over previous
//
#include <hip/hip_runtime.h>

#define Bb  128
#define Tt  512
#define Ff  512
#define Hh  1024
#define BH  (Bb*Hh)
#define WGS 512
#define NCU 192

// ws offsets (bytes)
#define OFF_H1   0u
#define OFF_H2   524288u
#define OFF_H2F  1048576u
#define OFF_PB   1572864u       // [2][64][128][64] f32 = 4 MB
#define OFF_BAR  5767168u
#define OFF_WB   5771264u       // [256 nt][16 ch][64 lane][8] bf16 = 4 MB
#define WS_USED  9965568u

typedef __attribute__((ext_vector_type(8))) short short8;
typedef __attribute__((ext_vector_type(4))) float f32x4;

__device__ __forceinline__ short f2bf(float f){
  union { float fv; unsigned u; } v; v.fv = f;
  unsigned r = v.u + 0x7fffu + ((v.u >> 16) & 1u);   // RNE
  return (short)(r >> 16);
}

__device__ __forceinline__ f32x4 mfma16(short8 a, short8 b, f32x4 c){
  return __builtin_amdgcn_mfma_f32_16x16x32_bf16(a, b, c, 0, 0, 0);
}

__device__ __forceinline__ void gridbar(unsigned* cnt, unsigned target){
  __syncthreads();
  if (threadIdx.x == 0){
    __hip_atomic_fetch_add(cnt, 1u, __ATOMIC_RELEASE, __HIP_MEMORY_SCOPE_AGENT);
    while (__hip_atomic_load(cnt, __ATOMIC_RELAXED, __HIP_MEMORY_SCOPE_AGENT) < target)
      __builtin_amdgcn_s_sleep(1);
    (void)__hip_atomic_load(cnt, __ATOMIC_ACQUIRE, __HIP_MEMORY_SCOPE_AGENT);
  }
  __syncthreads();
}

// Wih1 fp32 [4096][512] -> bf16 global B-frag layout Wb[nt][ch][lane][8]
__global__ void __launch_bounds__(WGS) conv_wih1(const float* __restrict__ W,
                                                 short* __restrict__ Wb){
  const int fi   = blockIdx.x * WGS + threadIdx.x;     // 262144 frags
  const int nt   = fi >> 10;
  const int ch   = (fi >> 6) & 15;
  const int lane = fi & 63;
  const int grow = nt*16 + (lane & 15);
  const int k    = (ch << 5) + ((lane >> 4) << 3);
  const float* s = W + (size_t)grow * Ff + k;
  short8 v;
  #pragma unroll
  for (int e = 0; e < 8; ++e) v[e] = f2bf(s[e]);
  *(short8*)(Wb + (size_t)fi * 8) = v;
}

// Specialized persistent kernel. Groups by blockIdx.x:
//  [0,64)  A: layer-1 (x@Wih1 via Wb + h1@Whh1 in LDS) -> h1,c1
//  [64,128) B: PB = h1@Wih2 (LDS) -> fp32 partial
//  [128,192) C: gates2 = PB + h2@Whh2 (LDS) -> h2,c2
// Phase p: A does step p (p<T); B does PB[p-1] (1<=p<=T); C does step p-2 (p>=2).
__global__ void __launch_bounds__(WGS) lstm_spec(
    const float* __restrict__ x,
    const float* __restrict__ Whh1,
    const float* __restrict__ bih1, const float* __restrict__ bhh1,
    const float* __restrict__ Wih2, const float* __restrict__ Whh2,
    const float* __restrict__ bih2, const float* __restrict__ bhh2,
    const short* __restrict__ Wb,
    short* __restrict__ h1buf, short* __restrict__ h2buf,
    float* __restrict__ PB, float* __restrict__ h2f32,
    unsigned* __restrict__ barcnt)
{
  extern __shared__ short LW[];          // [4 g][32 ch][64 lane][8] bf16 = 128 KB
  const int bid = blockIdx.x, tid = threadIdx.x;
  const int grp = bid >> 6;              // 0=A, 1=B, 2=C
  const int cu  = bid & 63;
  const int c0  = cu << 4;               // owns h-cols [c0, c0+16)

  // ---- stage this CU's K=1024 weight matrix into LDS (B-frag layout) ----
  const float* Wsrc = (grp == 0) ? Whh1 : (grp == 1) ? Wih2 : Whh2;
  for (int fi = tid; fi < 8192; fi += WGS){
    const int g = fi >> 11, ch = (fi >> 6) & 31, ln = fi & 63;
    const int grow = (g << 10) + c0 + (ln & 15);
    const int k    = (ch << 5) + ((ln >> 4) << 3);
    const float* s = Wsrc + (size_t)grow * Hh + k;
    short8 v;
    #pragma unroll
    for (int e = 0; e < 8; ++e) v[e] = f2bf(s[e]);
    *(short8*)(LW + (size_t)fi * 8) = v;
  }
  __syncthreads();

  const int lane = tid & 63, wv = tid >> 6;
  const int r0   = (wv << 4) + (lane & 15);        // A-frag row (batch)
  const int kg8  = (lane >> 4) << 3;               // A-frag k-offset
  const int j    = lane & 15;                      // owned local col
  const int bb   = (wv << 4) + ((lane >> 4) << 2); // C/D base row
  const int gcol = c0 + j;

  float bsum[4], cst[4];
  #pragma unroll
  for (int g = 0; g < 4; ++g)
    bsum[g] = (grp == 0) ? bih1[(g << 10) + gcol] + bhh1[(g << 10) + gcol]
            : (grp == 2) ? bih2[(g << 10) + gcol] + bhh2[(g << 10) + gcol] : 0.f;
  #pragma unroll
  for (int r = 0; r < 4; ++r) cst[r] = 0.f;

  for (int p = 0; p <= Tt + 1; ++p){
    if (grp == 0 && p < Tt){
      f32x4 acc[4] = {{0,0,0,0},{0,0,0,0},{0,0,0,0},{0,0,0,0}};
      // x_t @ Wih1^T  (B-frags from global Wb, L2-resident)
      const float* xb = x + ((size_t)r0 * Tt + p) * Ff + kg8;
      #pragma unroll 2
      for (int ch = 0; ch < 16; ++ch){
        float4 u0 = *(const float4*)(xb + (ch << 5));
        float4 u1 = *(const float4*)(xb + (ch << 5) + 4);
        short8 a;
        a[0]=f2bf(u0.x); a[1]=f2bf(u0.y); a[2]=f2bf(u0.z); a[3]=f2bf(u0.w);
        a[4]=f2bf(u1.x); a[5]=f2bf(u1.y); a[6]=f2bf(u1.z); a[7]=f2bf(u1.w);
        #pragma unroll
        for (int g = 0; g < 4; ++g)
          acc[g] = mfma16(a, *(const short8*)(Wb + (size_t)(((((g << 6) + cu) << 4) + ch) * 64 + lane) * 8), acc[g]);
      }
      // h1[p-1] @ Whh1^T
      const short* hp = h1buf + ((p + 1) & 1) * BH + r0 * Hh + kg8;
      #pragma unroll 8
      for (int ch = 0; ch < 32; ++ch){
        short8 a = *(const short8*)(hp + (ch << 5));
        #pragma unroll
        for (int g = 0; g < 4; ++g)
          acc[g] = mfma16(a, *(const short8*)(LW + (size_t)((((g << 5) + ch) << 6) + lane) * 8), acc[g]);
      }
      // register-resident update -> h1[p]
      short* hw = h1buf + (p & 1) * BH;
      #pragma unroll
      for (int r = 0; r < 4; ++r){
        float gi = acc[0][r] + bsum[0], gf = acc[1][r] + bsum[1];
        float gg = acc[2][r] + bsum[2], go = acc[3][r] + bsum[3];
        float iv = 1.f/(1.f+__expf(-gi)), fv = 1.f/(1.f+__expf(-gf));
        float gv = tanhf(gg),             ov = 1.f/(1.f+__expf(-go));
        cst[r] = fv * cst[r] + iv * gv;
        hw[(size_t)(bb + r) * Hh + gcol] = f2bf(ov * tanhf(cst[r]));
      }
    } else if (grp == 1 && p >= 1 && p <= Tt){
      f32x4 acc[4] = {{0,0,0,0},{0,0,0,0},{0,0,0,0},{0,0,0,0}};
      // PB[p-1] = h1[p-1] @ Wih2^T
      const short* hp = h1buf + ((p + 1) & 1) * BH + r0 * Hh + kg8;
      #pragma unroll 8
      for (int ch = 0; ch < 32; ++ch){
        short8 a = *(const short8*)(hp + (ch << 5));
        #pragma unroll
        for (int g = 0; g < 4; ++g)
          acc[g] = mfma16(a, *(const short8*)(LW + (size_t)((((g << 5) + ch) << 6) + lane) * 8), acc[g]);
      }
      float* pw = PB + ((size_t)((p + 1) & 1) * 64 + cu) * (Bb * 64);
      #pragma unroll
      for (int g = 0; g < 4; ++g)
        #pragma unroll
        for (int r = 0; r < 4; ++r)
          pw[(size_t)(bb + r) * 64 + (g << 4) + j] = acc[g][r];
    } else if (grp == 2 && p >= 2){
      // gates2[p-2] = PB[p-2] + h2[p-3] @ Whh2^T
      const float* pr = PB + ((size_t)(p & 1) * 64 + cu) * (Bb * 64);
      f32x4 acc[4];
      #pragma unroll
      for (int g = 0; g < 4; ++g)
        #pragma unroll
        for (int r = 0; r < 4; ++r)
          acc[g][r] = pr[(size_t)(bb + r) * 64 + (g << 4) + j];
      const short* hp = h2buf + ((p + 1) & 1) * BH + r0 * Hh + kg8;
      #pragma unroll 8
      for (int ch = 0; ch < 32; ++ch){
        short8 a = *(const short8*)(hp + (ch << 5));
        #pragma unroll
        for (int g = 0; g < 4; ++g)
          acc[g] = mfma16(a, *(const short8*)(LW + (size_t)((((g << 5) + ch) << 6) + lane) * 8), acc[g]);
      }
      short* hw = h2buf + (p & 1) * BH;
      #pragma unroll
      for (int r = 0; r < 4; ++r){
        float gi = acc[0][r] + bsum[0], gf = acc[1][r] + bsum[1];
        float gg = acc[2][r] + bsum[2], go = acc[3][r] + bsum[3];
        float iv = 1.f/(1.f+__expf(-gi)), fv = 1.f/(1.f+__expf(-gf));
        float gv = tanhf(gg),             ov = 1.f/(1.f+__expf(-go));
        cst[r] = fv * cst[r] + iv * gv;
        float hv = ov * tanhf(cst[r]);
        hw[(size_t)(bb + r) * Hh + gcol] = f2bf(hv);
        if (p == Tt + 1) h2f32[(size_t)(bb + r) * Hh + gcol] = hv;  // final step fp32
      }
    }
    gridbar(barcnt, (unsigned)(NCU * (p + 1)));
  }
}

__global__ void final_linear(const float* __restrict__ h2, const float* __restrict__ Wl,
                             const float* __restrict__ bl, float* __restrict__ out){
  __shared__ float red[256];
  const int b = blockIdx.x, t = threadIdx.x;
  float s = 0.f;
  for (int k = t; k < Hh; k += 256) s += h2[(size_t)b * Hh + k] * Wl[k];
  red[t] = s; __syncthreads();
  for (int off = 128; off > 0; off >>= 1){ if (t < off) red[t] += red[t + off]; __syncthreads(); }
  if (t == 0) out[b] = red[0] + bl[0];
}

extern "C" void kernel_launch(void* const* d_in, const int* in_sizes, int n_in,
                              void* d_out, int out_size, void* d_ws, size_t ws_size,
                              hipStream_t stream) {
  (void)in_sizes; (void)n_in; (void)out_size;
  const float* x    = (const float*)d_in[0];
  const float* Wih1 = (const float*)d_in[1];
  const float* Whh1 = (const float*)d_in[2];
  const float* bih1 = (const float*)d_in[3];
  const float* bhh1 = (const float*)d_in[4];
  const float* Wih2 = (const float*)d_in[5];
  const float* Whh2 = (const float*)d_in[6];
  const float* bih2 = (const float*)d_in[7];
  const float* bhh2 = (const float*)d_in[8];
  const float* Wlin = (const float*)d_in[9];
  const float* blin = (const float*)d_in[10];
  float* out = (float*)d_out;

  if (ws_size < WS_USED) return;
  char* ws = (char*)d_ws;
  short*    h1buf  = (short*)(ws + OFF_H1);
  short*    h2buf  = (short*)(ws + OFF_H2);
  float*    h2f32  = (float*)(ws + OFF_H2F);
  float*    PB     = (float*)(ws + OFF_PB);
  unsigned* barcnt = (unsigned*)(ws + OFF_BAR);
  short*    Wb     = (short*)(ws + OFF_WB);

  hipMemsetAsync(d_ws, 0, OFF_WB, stream);   // zero h-state, PB, barrier
  conv_wih1<<<dim3(512), dim3(WGS), 0, stream>>>(Wih1, Wb);
  hipFuncSetAttribute(reinterpret_cast<const void*>(lstm_spec),
                      hipFuncAttributeMaxDynamicSharedMemorySize, 131072);
  lstm_spec<<<dim3(NCU), dim3(WGS), 131072, stream>>>(
      x, Whh1, bih1, bhh1, Wih2, Whh2, bih2, bhh2,
      Wb, h1buf, h2buf, PB, h2f32, barcnt);
  final_linear<<<dim3(Bb), dim3(256), 0, stream>>>(h2f32, Wlin, blin, out);
}

// Round 3
// 11724.503 us; speedup vs baseline: 1.4423x; 1.3778x over previous
//
#include <hip/hip_runtime.h>

#define Bb  128
#define Tt  512
#define Ff  512
#define Hh  1024
#define BH  (Bb*Hh)
#define WGS 512
#define NBLK 192

// ws offsets (bytes)
#define OFF_H1   0u
#define OFF_H2   524288u
#define OFF_H2F  1048576u
#define OFF_BAR  1572864u          // 4 KB counters: loc[i] @ i*256B, root @ 3072B
#define OFF_PB   1576960u          // [2][64 cu][8 wv][64 lane][16 f32] = 4 MB
#define OFF_WB   5771264u          // Wih1 bf16 frags, 4 MB
#define OFF_XB   9965568u          // x bf16, 64 MB
#define WS_MIN   9965568u
#define WS_FULL  77074432u

typedef __attribute__((ext_vector_type(8))) short short8;
typedef __attribute__((ext_vector_type(4))) float f32x4;

__device__ __forceinline__ short f2bf(float f){
  union { float fv; unsigned u; } v; v.fv = f;
  unsigned r = v.u + 0x7fffu + ((v.u >> 16) & 1u);   // RNE
  return (short)(r >> 16);
}

__device__ __forceinline__ f32x4 mfma16(short8 a, short8 b, f32x4 c){
  return __builtin_amdgcn_mfma_f32_16x16x32_bf16(a, b, c, 0, 0, 0);
}

// coherent (LLC) access: sc0 sc1 = bypass L1/L2, read/write coherence point
#define CLDH(dst, base, OFFB) \
  asm volatile("global_load_dwordx4 %0, %1, off offset:" #OFFB " sc0 sc1" \
               : "=v"(dst) : "v"(base) : "memory")
#define CLDF(dst, base, OFFB) \
  asm volatile("global_load_dwordx4 %0, %1, off offset:" #OFFB " sc0 sc1" \
               : "=v"(dst) : "v"(base) : "memory")
#define CSTF(base, val, OFFB) \
  asm volatile("global_store_dwordx4 %0, %1, off offset:" #OFFB " sc0 sc1" \
               :: "v"(base), "v"(val) : "memory")

__device__ __forceinline__ void st_bf16_coh(short* p, short v){
  asm volatile("global_store_short %0, %1, off sc0 sc1"
               :: "v"(p), "v"((unsigned)(unsigned short)v) : "memory");
}

// Wih1 fp32 [4096][512] -> bf16 B-frag layout Wb[nt=256][ch=16][lane=64][8]
__global__ void __launch_bounds__(WGS) conv_wih1(const float* __restrict__ W,
                                                 short* __restrict__ Wb){
  const int fi   = blockIdx.x * WGS + threadIdx.x;
  const int nt   = fi >> 10;
  const int ch   = (fi >> 6) & 15;
  const int lane = fi & 63;
  const int grow = nt*16 + (lane & 15);
  const int k    = (ch << 5) + ((lane >> 4) << 3);
  const float* s = W + (size_t)grow * Ff + k;
  short8 v;
  #pragma unroll
  for (int e = 0; e < 8; ++e) v[e] = f2bf(s[e]);
  *(short8*)(Wb + (size_t)fi * 8) = v;
}

__global__ void __launch_bounds__(WGS) conv_x(const float* __restrict__ xf,
                                              short* __restrict__ xb){
  const size_t i = ((size_t)blockIdx.x * WGS + threadIdx.x) * 8;
  float4 u0 = *(const float4*)(xf + i);
  float4 u1 = *(const float4*)(xf + i + 4);
  short8 v;
  v[0]=f2bf(u0.x); v[1]=f2bf(u0.y); v[2]=f2bf(u0.z); v[3]=f2bf(u0.w);
  v[4]=f2bf(u1.x); v[5]=f2bf(u1.y); v[6]=f2bf(u1.z); v[7]=f2bf(u1.w);
  *(short8*)(xb + i) = v;
}

// Groups: [0,64) A: layer-1; [64,128) B: PB=h1@Wih2; [128,192) C: layer-2.
// Phase p: A step p (p<T); B PB[p-1] (1<=p<=T); C step p-2 (2<=p<=T+1).
__global__ void __launch_bounds__(WGS) lstm_spec(
    const float* __restrict__ x, const short* __restrict__ xb, int use_xb,
    const float* __restrict__ Whh1,
    const float* __restrict__ bih1, const float* __restrict__ bhh1,
    const float* __restrict__ Wih2, const float* __restrict__ Whh2,
    const float* __restrict__ bih2, const float* __restrict__ bhh2,
    const short* __restrict__ Wb,
    short* __restrict__ h1buf, short* __restrict__ h2buf,
    float* __restrict__ PB, float* __restrict__ h2f32,
    unsigned* __restrict__ bar)
{
  extern __shared__ short LW[];          // [4 g][32 ch][64 lane][8] bf16 = 128 KB
  const int bid = blockIdx.x, tid = threadIdx.x;
  const int grp = bid >> 6;              // 0=A, 1=B, 2=C
  const int cu  = bid & 63;
  const int c0  = cu << 4;

  // stage this group's K=1024 weight matrix into LDS (B-frag layout)
  const float* Wsrc = (grp == 0) ? Whh1 : (grp == 1) ? Wih2 : Whh2;
  for (int fi = tid; fi < 8192; fi += WGS){
    const int g = fi >> 11, ch = (fi >> 6) & 31, ln = fi & 63;
    const int grow = (g << 10) + c0 + (ln & 15);
    const int k    = (ch << 5) + ((ln >> 4) << 3);
    const float* s = Wsrc + (size_t)grow * Hh + k;
    short8 v;
    #pragma unroll
    for (int e = 0; e < 8; ++e) v[e] = f2bf(s[e]);
    *(short8*)(LW + (size_t)fi * 8) = v;
  }
  __syncthreads();

  const int lane = tid & 63, wv = tid >> 6;
  const int r0   = (wv << 4) + (lane & 15);
  const int kg8  = (lane >> 4) << 3;
  const int j    = lane & 15;
  const int bb   = (wv << 4) + ((lane >> 4) << 2);
  const int gcol = c0 + j;
  const int slot = bid & 7;

  float bsum[4], cst[4];
  #pragma unroll
  for (int g = 0; g < 4; ++g)
    bsum[g] = (grp == 0) ? bih1[(g << 10) + gcol] + bhh1[(g << 10) + gcol]
            : (grp == 2) ? bih2[(g << 10) + gcol] + bhh2[(g << 10) + gcol] : 0.f;
  #pragma unroll
  for (int r = 0; r < 4; ++r) cst[r] = 0.f;

  for (int p = 0; p <= Tt + 1; ++p){
    if (grp == 0 && p < Tt){
      f32x4 acc[4] = {{0,0,0,0},{0,0,0,0},{0,0,0,0},{0,0,0,0}};
      const short* hp  = h1buf + ((p + 1) & 1) * BH + r0 * Hh + kg8;
      const short* xbp = xb + ((size_t)r0 * Tt + p) * Ff + kg8;
      const float* xfp = x  + ((size_t)r0 * Tt + p) * Ff + kg8;
      #pragma unroll
      for (int cb = 0; cb < 4; ++cb){
        const short* hc = hp + (cb << 8);
        short8 hb[8];
        CLDH(hb[0], hc, 0);   CLDH(hb[1], hc, 64);  CLDH(hb[2], hc, 128);
        CLDH(hb[3], hc, 192); CLDH(hb[4], hc, 256); CLDH(hb[5], hc, 320);
        CLDH(hb[6], hc, 384); CLDH(hb[7], hc, 448);
        short8 xa[4];
        if (use_xb){
          #pragma unroll
          for (int u = 0; u < 4; ++u)
            xa[u] = *(const short8*)(xbp + (cb << 7) + (u << 5));
        } else {
          #pragma unroll
          for (int u = 0; u < 4; ++u){
            float4 u0 = *(const float4*)(xfp + (cb << 7) + (u << 5));
            float4 u1 = *(const float4*)(xfp + (cb << 7) + (u << 5) + 4);
            xa[u][0]=f2bf(u0.x); xa[u][1]=f2bf(u0.y); xa[u][2]=f2bf(u0.z); xa[u][3]=f2bf(u0.w);
            xa[u][4]=f2bf(u1.x); xa[u][5]=f2bf(u1.y); xa[u][6]=f2bf(u1.z); xa[u][7]=f2bf(u1.w);
          }
        }
        asm volatile("s_waitcnt vmcnt(0)" ::: "memory");
        __builtin_amdgcn_sched_barrier(0);
        #pragma unroll
        for (int g = 0; g < 4; ++g){
          #pragma unroll
          for (int u = 0; u < 8; ++u)
            acc[g] = mfma16(hb[u], *(const short8*)(LW + ((size_t)(((g<<5)+(cb<<3)+u)<<6) + lane)*8), acc[g]);
          #pragma unroll
          for (int u = 0; u < 4; ++u)
            acc[g] = mfma16(xa[u], *(const short8*)(Wb + ((size_t)((((g<<6)+cu)<<4)+(cb<<2)+u)*64 + lane)*8), acc[g]);
        }
      }
      short* hw = h1buf + (p & 1) * BH;
      #pragma unroll
      for (int r = 0; r < 4; ++r){
        float gi = acc[0][r] + bsum[0], gf = acc[1][r] + bsum[1];
        float gg = acc[2][r] + bsum[2], go = acc[3][r] + bsum[3];
        float iv = 1.f/(1.f+__expf(-gi)), fv = 1.f/(1.f+__expf(-gf));
        float gv = tanhf(gg),             ov = 1.f/(1.f+__expf(-go));
        cst[r] = fv * cst[r] + iv * gv;
        st_bf16_coh(hw + (size_t)(bb + r) * Hh + gcol, f2bf(ov * tanhf(cst[r])));
      }
    } else if (grp == 1 && p >= 1 && p <= Tt){
      f32x4 acc[4] = {{0,0,0,0},{0,0,0,0},{0,0,0,0},{0,0,0,0}};
      const short* hp = h1buf + ((p + 1) & 1) * BH + r0 * Hh + kg8;
      #pragma unroll
      for (int cb = 0; cb < 4; ++cb){
        const short* hc = hp + (cb << 8);
        short8 hb[8];
        CLDH(hb[0], hc, 0);   CLDH(hb[1], hc, 64);  CLDH(hb[2], hc, 128);
        CLDH(hb[3], hc, 192); CLDH(hb[4], hc, 256); CLDH(hb[5], hc, 320);
        CLDH(hb[6], hc, 384); CLDH(hb[7], hc, 448);
        asm volatile("s_waitcnt vmcnt(0)" ::: "memory");
        __builtin_amdgcn_sched_barrier(0);
        #pragma unroll
        for (int g = 0; g < 4; ++g)
          #pragma unroll
          for (int u = 0; u < 8; ++u)
            acc[g] = mfma16(hb[u], *(const short8*)(LW + ((size_t)(((g<<5)+(cb<<3)+u)<<6) + lane)*8), acc[g]);
      }
      float* pw = PB + (((size_t)((p + 1) & 1) * 64 + cu) * 8 + wv) * 1024 + lane * 16;
      CSTF(pw, acc[0], 0); CSTF(pw, acc[1], 16); CSTF(pw, acc[2], 32); CSTF(pw, acc[3], 48);
    } else if (grp == 2 && p >= 2){
      const float* pr = PB + (((size_t)(p & 1) * 64 + cu) * 8 + wv) * 1024 + lane * 16;
      f32x4 acc[4];
      CLDF(acc[0], pr, 0); CLDF(acc[1], pr, 16); CLDF(acc[2], pr, 32); CLDF(acc[3], pr, 48);
      const short* hp = h2buf + ((p + 1) & 1) * BH + r0 * Hh + kg8;
      #pragma unroll
      for (int cb = 0; cb < 4; ++cb){
        const short* hc = hp + (cb << 8);
        short8 hb[8];
        CLDH(hb[0], hc, 0);   CLDH(hb[1], hc, 64);  CLDH(hb[2], hc, 128);
        CLDH(hb[3], hc, 192); CLDH(hb[4], hc, 256); CLDH(hb[5], hc, 320);
        CLDH(hb[6], hc, 384); CLDH(hb[7], hc, 448);
        asm volatile("s_waitcnt vmcnt(0)" ::: "memory");
        __builtin_amdgcn_sched_barrier(0);
        #pragma unroll
        for (int g = 0; g < 4; ++g)
          #pragma unroll
          for (int u = 0; u < 8; ++u)
            acc[g] = mfma16(hb[u], *(const short8*)(LW + ((size_t)(((g<<5)+(cb<<3)+u)<<6) + lane)*8), acc[g]);
      }
      short* hw = h2buf + (p & 1) * BH;
      #pragma unroll
      for (int r = 0; r < 4; ++r){
        float gi = acc[0][r] + bsum[0], gf = acc[1][r] + bsum[1];
        float gg = acc[2][r] + bsum[2], go = acc[3][r] + bsum[3];
        float iv = 1.f/(1.f+__expf(-gi)), fv = 1.f/(1.f+__expf(-gf));
        float gv = tanhf(gg),             ov = 1.f/(1.f+__expf(-go));
        cst[r] = fv * cst[r] + iv * gv;
        float hv = ov * tanhf(cst[r]);
        st_bf16_coh(hw + (size_t)(bb + r) * Hh + gcol, f2bf(hv));
        if (p == Tt + 1) h2f32[(size_t)(bb + r) * Hh + gcol] = hv;
      }
    }

    // two-level all-relaxed barrier (no L2 writeback/invalidate)
    __syncthreads();                       // drains vmcnt -> sc-stores at LLC
    if (tid == 0){
      unsigned prev = __hip_atomic_fetch_add(bar + (slot << 6), 1u,
                        __ATOMIC_RELAXED, __HIP_MEMORY_SCOPE_AGENT);
      if (prev == (unsigned)(24 * (p + 1)) - 1u)
        __hip_atomic_fetch_add(bar + 768, 1u,
                        __ATOMIC_RELAXED, __HIP_MEMORY_SCOPE_AGENT);
      while (__hip_atomic_load(bar + 768,
                        __ATOMIC_RELAXED, __HIP_MEMORY_SCOPE_AGENT)
             < (unsigned)(8 * (p + 1)))
        __builtin_amdgcn_s_sleep(2);
    }
    __syncthreads();
  }
}

__global__ void final_linear(const float* __restrict__ h2, const float* __restrict__ Wl,
                             const float* __restrict__ bl, float* __restrict__ out){
  __shared__ float red[256];
  const int b = blockIdx.x, t = threadIdx.x;
  float s = 0.f;
  for (int k = t; k < Hh; k += 256) s += h2[(size_t)b * Hh + k] * Wl[k];
  red[t] = s; __syncthreads();
  for (int off = 128; off > 0; off >>= 1){ if (t < off) red[t] += red[t + off]; __syncthreads(); }
  if (t == 0) out[b] = red[0] + bl[0];
}

extern "C" void kernel_launch(void* const* d_in, const int* in_sizes, int n_in,
                              void* d_out, int out_size, void* d_ws, size_t ws_size,
                              hipStream_t stream) {
  (void)in_sizes; (void)n_in; (void)out_size;
  const float* x    = (const float*)d_in[0];
  const float* Wih1 = (const float*)d_in[1];
  const float* Whh1 = (const float*)d_in[2];
  const float* bih1 = (const float*)d_in[3];
  const float* bhh1 = (const float*)d_in[4];
  const float* Wih2 = (const float*)d_in[5];
  const float* Whh2 = (const float*)d_in[6];
  const float* bih2 = (const float*)d_in[7];
  const float* bhh2 = (const float*)d_in[8];
  const float* Wlin = (const float*)d_in[9];
  const float* blin = (const float*)d_in[10];
  float* out = (float*)d_out;

  if (ws_size < WS_MIN) return;
  const int use_xb = (ws_size >= WS_FULL) ? 1 : 0;

  char* ws = (char*)d_ws;
  short*    h1buf = (short*)(ws + OFF_H1);
  short*    h2buf = (short*)(ws + OFF_H2);
  float*    h2f32 = (float*)(ws + OFF_H2F);
  unsigned* bar   = (unsigned*)(ws + OFF_BAR);
  float*    PB    = (float*)(ws + OFF_PB);
  short*    Wb    = (short*)(ws + OFF_WB);
  short*    xb    = (short*)(ws + OFF_XB);

  hipMemsetAsync(d_ws, 0, OFF_WB, stream);    // h-state, barrier, PB
  conv_wih1<<<dim3(512), dim3(WGS), 0, stream>>>(Wih1, Wb);
  if (use_xb) conv_x<<<dim3(8192), dim3(WGS), 0, stream>>>(x, xb);
  hipFuncSetAttribute(reinterpret_cast<const void*>(lstm_spec),
                      hipFuncAttributeMaxDynamicSharedMemorySize, 131072);
  lstm_spec<<<dim3(NBLK), dim3(WGS), 131072, stream>>>(
      x, use_xb ? xb : Wb, use_xb, Whh1, bih1, bhh1, Wih2, Whh2, bih2, bhh2,
      Wb, h1buf, h2buf, PB, h2f32, bar);
  final_linear<<<dim3(Bb), dim3(256), 0, stream>>>(h2f32, Wlin, blin, out);
}

// Round 5
// 9455.810 us; speedup vs baseline: 1.7884x; 1.2399x over previous
//
#include <hip/hip_runtime.h>

#define Bb  128
#define Tt  512
#define Ff  512
#define Hh  1024
#define BH  (Bb*Hh)
#define WGS 512
#define NBLK 256
#define NPH 515
#define PBH (128*4096)

#define OFF_H1   0u
#define OFF_H2   524288u
#define OFF_H2F  1048576u
#define OFF_BAR  1572864u
#define OFF_PB   1576960u
#define OFF_PBX  5771264u
#define OFF_XB   9965568u
#define WS_NEED  77074432u

typedef __attribute__((ext_vector_type(8))) short short8;
typedef __attribute__((ext_vector_type(4))) float f32x4;
typedef __attribute__((ext_vector_type(16))) float f32x16;

__device__ __forceinline__ short f2bf(float f){
  union { float fv; unsigned u; } v; v.fv = f;
  unsigned r = v.u + 0x7fffu + ((v.u >> 16) & 1u);   // RNE
  return (short)(r >> 16);
}
__device__ __forceinline__ float sigm(float x){ return 1.f/(1.f+__expf(-x)); }

__device__ __forceinline__ f32x16 mfma32(short8 a, short8 b, f32x16 c){
  return __builtin_amdgcn_mfma_f32_32x32x16_bf16(a, b, c, 0, 0, 0);
}

// coherent (LLC) ops: sc0 sc1 bypass L1/L2
__device__ __forceinline__ short8 scld8(const short* p){
  short8 d;
  asm volatile("global_load_dwordx4 %0, %1, off sc0 sc1" : "=v"(d) : "v"(p) : "memory");
  return d;
}
__device__ __forceinline__ f32x4 scldf4(const float* p){
  f32x4 d;
  asm volatile("global_load_dwordx4 %0, %1, off sc0 sc1" : "=v"(d) : "v"(p) : "memory");
  return d;
}
__device__ __forceinline__ void sstf4(float* p, f32x4 v){
  asm volatile("global_store_dwordx4 %0, %1, off sc0 sc1" :: "v"(p), "v"(v) : "memory");
}
__device__ __forceinline__ void ssth(short* p, short v){
  asm volatile("global_store_short %0, %1, off sc0 sc1"
               :: "v"(p), "v"((unsigned)(unsigned short)v) : "memory");
}
__device__ __forceinline__ void drain_vm(){
  asm volatile("s_waitcnt vmcnt(0)" ::: "memory");
  __builtin_amdgcn_sched_barrier(0);
}

__global__ void __launch_bounds__(WGS) conv_x(const float* __restrict__ xf,
                                              short* __restrict__ xb){
  const size_t i = ((size_t)blockIdx.x * WGS + threadIdx.x) * 8;
  float4 u0 = *(const float4*)(xf + i);
  float4 u1 = *(const float4*)(xf + i + 4);
  short8 v;
  v[0]=f2bf(u0.x); v[1]=f2bf(u0.y); v[2]=f2bf(u0.z); v[3]=f2bf(u0.w);
  v[4]=f2bf(u1.x); v[5]=f2bf(u1.y); v[6]=f2bf(u1.z); v[7]=f2bf(u1.w);
  *(short8*)(xb + i) = v;
}

// Groups (bid>>6): 0=A layer1-h, 1=B PB=h1@Wih2, 2=C layer2, 3=X PBX=x@Wih1
// Phase p: X: gx[p] (p<512); A: step p-1 (1..512); B: PB step p-2 (2..513); C: step p-3 (3..514)
__global__ void __launch_bounds__(WGS, 2) lstm4(
    const short* __restrict__ xb,
    const float* __restrict__ Wih1, const float* __restrict__ Whh1,
    const float* __restrict__ bih1, const float* __restrict__ bhh1,
    const float* __restrict__ Wih2, const float* __restrict__ Whh2,
    const float* __restrict__ bih2, const float* __restrict__ bhh2,
    short* __restrict__ h1, short* __restrict__ h2,
    float* __restrict__ PB, float* __restrict__ PBX,
    float* __restrict__ h2f32, unsigned* __restrict__ bar)
{
  extern __shared__ char lds[];          // [0,128K) stage dbuf / F-alias, [128K,+256) bias
  float* F  = (float*)lds;
  float* Lb = (float*)(lds + 131072);

  const int bid = blockIdx.x, tid = threadIdx.x;
  const int grp = bid >> 6;
  const int cu  = bid & 63;
  const int c0h = cu << 4;               // 16 h-cols per CU
  const int lane = tid & 63, wv = tid >> 6;
  const int tc = lane & 31, hi = lane >> 5;
  const int slot = bid & 7;

  // wave decomposition
  const int cth = wv & 1;
  const int kh  = (wv >> 1) & 1;         // ABC only
  const int rh  = wv >> 2;               // ABC only
  const int xrt = wv >> 1;               // X only

  // bias into LDS (A: b1 sums, C: b2 sums)
  if (tid < 64){
    const int hc = tid >> 2, g = tid & 3;
    float v = 0.f;
    if (grp == 0) v = bih1[(g<<10) + c0h + hc] + bhh1[(g<<10) + c0h + hc];
    if (grp == 2) v = bih2[(g<<10) + c0h + hc] + bhh2[(g<<10) + c0h + hc];
    Lb[tid] = v;
  }

  // ---- load this wave's B-fragments into VGPRs (once, fp32 -> bf16) ----
  const float* Wsrc = (grp==0) ? Whh1 : (grp==1) ? Wih2 : (grp==2) ? Whh2 : Wih1;
  const int Kdim = (grp==3) ? Ff : Hh;
  const int kb0  = (grp==3) ? 0 : kh*512;
  const int wrow = (tc&3)*Hh + c0h + cth*8 + (tc>>2);   // gate-interleaved cols
  short8 bfr[32];
  #pragma unroll
  for (int f = 0; f < 32; ++f){
    const float* s = Wsrc + (size_t)wrow*Kdim + kb0 + f*16 + hi*8;
    float4 u0 = *(const float4*)(s);
    float4 u1 = *(const float4*)(s + 4);
    short8 v;
    v[0]=f2bf(u0.x); v[1]=f2bf(u0.y); v[2]=f2bf(u0.z); v[3]=f2bf(u0.w);
    v[4]=f2bf(u1.x); v[5]=f2bf(u1.y); v[6]=f2bf(u1.z); v[7]=f2bf(u1.w);
    bfr[f] = v;
  }
  __syncthreads();

  float cst[4] = {0.f, 0.f, 0.f, 0.f};
  const int swz = (lane & 31) << 4;

  for (int p = 0; p < NPH; ++p){
    const bool act = (grp==0) ? (p>=1 && p<=512)
                   : (grp==1) ? (p>=2 && p<=513)
                   : (grp==2) ? (p>=3 && p<=514)
                   :            (p < 512);
    const short* sh = (grp==2) ? (h2 + (p&1)*BH) : (h1 + (p&1)*BH);

    // BUGFIX (R4): preload PB/PBX slabs EARLY; completed by the staging
    // loop's drain_vm() (vmcnt(0)+sched_barrier) long before their use in
    // the update. R4 consumed these asm loads with no intervening waitcnt.
    f32x4 pre[4] = {{0,0,0,0},{0,0,0,0},{0,0,0,0},{0,0,0,0}};
    if (act && (grp == 0 || grp == 2)){
      const float* src = (grp == 0) ? (PBX + (size_t)((p+1)&1)*PBH)
                                    : (PB  + (size_t)((p+1)&1)*PBH);
      #pragma unroll
      for (int s4 = 0; s4 < 4; ++s4){
        const int id = (s4<<9) + tid;
        pre[s4] = scldf4(src + (size_t)(id>>4)*4096 + ((c0h + (id&15))<<2));
      }
    }

    f32x16 a0, a1;
    #pragma unroll
    for (int i = 0; i < 16; ++i){ a0[i] = 0.f; a1[i] = 0.f; }

    #pragma unroll
    for (int r = 0; r < 2; ++r){
      // ---- stage ----
      if (act){
        if (grp != 3){
          #pragma unroll
          for (int buf = 0; buf < 2; ++buf){
            const int kq = 2*buf + r;
            short8 t[8];
            #pragma unroll
            for (int i = 0; i < 8; ++i){
              const int u = (i<<9) + tid;
              t[i] = scld8(sh + (size_t)(u>>5)*Hh + kq*256 + (u&31)*8);
            }
            drain_vm();
            #pragma unroll
            for (int i = 0; i < 8; ++i){
              const int u = (i<<9) + tid;
              *(short8*)(lds + buf*65536 + (((u<<4)) ^ ((((u>>5)&31))<<4))) = t[i];
            }
          }
        } else {
          short8 t[8];
          #pragma unroll
          for (int i = 0; i < 8; ++i){
            const int u = (i<<9) + tid;
            t[i] = *(const short8*)(xb + ((size_t)(u>>5)*Tt + p)*Ff + r*256 + (u&31)*8);
          }
          #pragma unroll
          for (int i = 0; i < 8; ++i){
            const int u = (i<<9) + tid;
            *(short8*)(lds + r*65536 + (((u<<4)) ^ ((((u>>5)&31))<<4))) = t[i];
          }
        }
      }
      __syncthreads();
      // ---- compute ----
      if (act){
        if (grp != 3){
          const int row0 = rh*64 + (lane & 31);
          const char* b0 = lds + kh*65536 + row0*512;
          const char* b1 = b0 + 32*512;
          #pragma unroll
          for (int ci = 0; ci < 16; ++ci){
            const int ko = (((ci<<5) | (hi<<4)) ^ swz);
            short8 A0 = *(const short8*)(b0 + ko);
            short8 A1 = *(const short8*)(b1 + ko);
            a0 = mfma32(A0, bfr[r*16+ci], a0);
            a1 = mfma32(A1, bfr[r*16+ci], a1);
          }
        } else {
          const int row0 = xrt*32 + (lane & 31);
          const char* b0 = lds + r*65536 + row0*512;
          #pragma unroll
          for (int ci = 0; ci < 16; ++ci){
            const int ko = (((ci<<5) | (hi<<4)) ^ swz);
            short8 A0 = *(const short8*)(b0 + ko);
            a0 = mfma32(A0, bfr[r*16+ci], a0);
          }
        }
      }
      __syncthreads();
    }

    // ---- dump partials to F [2kh][128 rows][68] (gate-interleaved cols) ----
    if (act){
      const int colf = (cth<<5) + tc;
      if (grp != 3){
        #pragma unroll
        for (int rg = 0; rg < 16; ++rg){
          const int rl = (rg&3) + ((rg>>2)<<3) + (hi<<2);
          F[(kh*128 + rh*64 + rl)*68 + colf]      = a0[rg];
          F[(kh*128 + rh*64 + 32 + rl)*68 + colf] = a1[rg];
        }
      } else {
        #pragma unroll
        for (int rg = 0; rg < 16; ++rg){
          const int rl = (rg&3) + ((rg>>2)<<3) + (hi<<2);
          F[(xrt*32 + rl)*68 + colf] = a0[rg];
        }
      }
    }
    __syncthreads();

    // ---- update / exchange ----
    if (act){
      #pragma unroll
      for (int s = 0; s < 4; ++s){
        const int id  = (s<<9) + tid;
        const int row = id >> 4, hc = id & 15;
        const int gc4 = (c0h + hc) << 2;
        f32x4 q = *(f32x4*)&F[row*68 + (hc<<2)];
        if (grp != 3) q += *(f32x4*)&F[(128+row)*68 + (hc<<2)];
        if (grp == 0){
          f32x4 bb = *(f32x4*)&Lb[hc<<2];
          float gi=q[0]+pre[s][0]+bb[0], gf=q[1]+pre[s][1]+bb[1];
          float gg=q[2]+pre[s][2]+bb[2], go=q[3]+pre[s][3]+bb[3];
          float iv=sigm(gi), fv=sigm(gf), gv=tanhf(gg), ov=sigm(go);
          cst[s] = fv*cst[s] + iv*gv;
          ssth(h1 + ((p+1)&1)*BH + row*Hh + c0h + hc, f2bf(ov*tanhf(cst[s])));
        } else if (grp == 1){
          sstf4(PB + (size_t)(p&1)*PBH + row*4096 + gc4, q);
        } else if (grp == 2){
          f32x4 bb = *(f32x4*)&Lb[hc<<2];
          float gi=q[0]+pre[s][0]+bb[0], gf=q[1]+pre[s][1]+bb[1];
          float gg=q[2]+pre[s][2]+bb[2], go=q[3]+pre[s][3]+bb[3];
          float iv=sigm(gi), fv=sigm(gf), gv=tanhf(gg), ov=sigm(go);
          cst[s] = fv*cst[s] + iv*gv;
          float hv = ov*tanhf(cst[s]);
          ssth(h2 + ((p+1)&1)*BH + row*Hh + c0h + hc, f2bf(hv));
          if (p == 514) h2f32[row*Hh + c0h + hc] = hv;
        } else {
          sstf4(PBX + (size_t)(p&1)*PBH + row*4096 + gc4, q);
        }
      }
    }

    // ---- two-level relaxed grid barrier ----
    __syncthreads();
    if (tid == 0){
      unsigned prev = __hip_atomic_fetch_add(bar + (slot<<6), 1u,
                        __ATOMIC_RELAXED, __HIP_MEMORY_SCOPE_AGENT);
      if (prev == 32u*(p+1) - 1u)
        __hip_atomic_fetch_add(bar + 768, 1u,
                        __ATOMIC_RELAXED, __HIP_MEMORY_SCOPE_AGENT);
      while (__hip_atomic_load(bar + 768,
                        __ATOMIC_RELAXED, __HIP_MEMORY_SCOPE_AGENT) < 8u*(p+1))
        __builtin_amdgcn_s_sleep(1);
    }
    __syncthreads();
  }
}

__global__ void final_linear(const float* __restrict__ h2, const float* __restrict__ Wl,
                             const float* __restrict__ bl, float* __restrict__ out){
  __shared__ float red[256];
  const int b = blockIdx.x, t = threadIdx.x;
  float s = 0.f;
  for (int k = t; k < Hh; k += 256) s += h2[(size_t)b*Hh + k] * Wl[k];
  red[t] = s; __syncthreads();
  for (int off = 128; off > 0; off >>= 1){ if (t < off) red[t] += red[t+off]; __syncthreads(); }
  if (t == 0) out[b] = red[0] + bl[0];
}

extern "C" void kernel_launch(void* const* d_in, const int* in_sizes, int n_in,
                              void* d_out, int out_size, void* d_ws, size_t ws_size,
                              hipStream_t stream) {
  (void)in_sizes; (void)n_in; (void)out_size;
  const float* x    = (const float*)d_in[0];
  const float* Wih1 = (const float*)d_in[1];
  const float* Whh1 = (const float*)d_in[2];
  const float* bih1 = (const float*)d_in[3];
  const float* bhh1 = (const float*)d_in[4];
  const float* Wih2 = (const float*)d_in[5];
  const float* Whh2 = (const float*)d_in[6];
  const float* bih2 = (const float*)d_in[7];
  const float* bhh2 = (const float*)d_in[8];
  const float* Wlin = (const float*)d_in[9];
  const float* blin = (const float*)d_in[10];
  float* out = (float*)d_out;

  if (ws_size < WS_NEED) return;
  char* ws = (char*)d_ws;
  short*    h1b   = (short*)(ws + OFF_H1);
  short*    h2b   = (short*)(ws + OFF_H2);
  float*    h2f32 = (float*)(ws + OFF_H2F);
  unsigned* bar   = (unsigned*)(ws + OFF_BAR);
  float*    PB    = (float*)(ws + OFF_PB);
  float*    PBX   = (float*)(ws + OFF_PBX);
  short*    xb    = (short*)(ws + OFF_XB);

  hipMemsetAsync(d_ws, 0, OFF_PB, stream);   // h-state, h2f32, barrier
  conv_x<<<dim3(8192), dim3(WGS), 0, stream>>>(x, xb);
  hipFuncSetAttribute(reinterpret_cast<const void*>(lstm4),
                      hipFuncAttributeMaxDynamicSharedMemorySize, 131584);
  lstm4<<<dim3(NBLK), dim3(WGS), 131584, stream>>>(
      xb, Wih1, Whh1, bih1, bhh1, Wih2, Whh2, bih2, bhh2,
      h1b, h2b, PB, PBX, h2f32, bar);
  final_linear<<<dim3(Bb), dim3(256), 0, stream>>>(h2f32, Wlin, blin, out);
}